// Round 10
// baseline (165.835 us; speedup 1.0000x reference)
//
#include <hip/hip_runtime.h>
#include <math.h>

// OHNM loss: pos BCE sum + top-k(600000) negative softplus sum, mean over 800000.
//
// R10: 3 dispatches.
//  k_main (2048x256): zero-atomic stream pass (R7-proven): pos partial sums +
//    per-WAVE private cand regions via ballot cursor, plain stores. NO padding
//    zero-fill (consumers skip via per-wave count table in LDS).
//  k_h1 (256x1024): derive_hard; per-block PURE-STORE partial hists over cand:
//    counts + softplus-sums per bin. Bins: min((k-K0)>>14, 1023) — exact over
//    x in [1,4); clamp bin (x>=4, ~32 keys) is always sure territory.
//  k_h2 (64x1024): coalesced redundant scan of 256 partials (1 MB, L2-hot) ->
//    (b1,r1); stream cand once: boundary-bin keys -> LDS -> side buffer (ONE
//    global atomic per block); fold pos-slice + fsum-above-b1 slice into a
//    private slot; __threadfence + ticket; LAST block coherently reads slots +
//    side keys (atomic-RMW reads) and runs an exact 3-level (11/11/10-bit)
//    full-key LDS radix select -> out. (R4-proven ticket pattern.)
// hard mode (cand shortfall / region or side overflow / boundary bin > LDS):
// winner streams x,y directly through the same generic select — exact for ANY
// input, never taken here.

#define K0 0xBF800000u             // f2key(1.0f)
#define NWAVES 8192                // k_main: 2048 blocks x 4 waves
#define REG 256                    // cand words per wave (lambda=159)
#define NP 256                     // k_h1 blocks / partial hists
#define NH2 64                     // k_h2 blocks
#define NB 1024                    // L1 bins
#define LBUF 4096                  // boundary staging (words)
#define SIDE_CAP_MAX (1u << 20)

// ---- ws layout (word offsets) ----
#define OFF_SIDE_CNT 0
#define OFF_FLAGS    1
#define OFF_TICKET   2
#define OFF_SLOT     64                      // 64 floats
#define OFF_CNT      128                     // 8192 per-wave counts (|ovf<<31)
#define OFF_POSP     (OFF_CNT + NWAVES)      // 8192 floats
#define OFF_HC       (OFF_POSP + NWAVES)     // 256 x 1024 counts
#define OFF_HF       (OFF_HC + NP * NB)      // 256 x 1024 floats
#define OFF_SIDE     (OFF_HF + NP * NB)      // side key buffer
#define OFF_CAND     (OFF_SIDE + SIDE_CAP_MAX)
#define CANDW        (NWAVES * REG)          // 2,097,152 words (8 MB)

__device__ __forceinline__ unsigned f2key(float x) {
    unsigned u = __float_as_uint(x);
    return (u & 0x80000000u) ? ~u : (u | 0x80000000u);
}
__device__ __forceinline__ float key2f(unsigned k) {
    unsigned u = (k & 0x80000000u) ? (k & 0x7FFFFFFFu) : ~k;
    return __uint_as_float(u);
}
__device__ __forceinline__ float softplusf(float x) {
    return fmaxf(x, 0.0f) + __logf(1.0f + __expf(-fabsf(x)));
}
__device__ __forceinline__ float wred(float v) {
    v += __shfl_down(v, 32); v += __shfl_down(v, 16); v += __shfl_down(v, 8);
    v += __shfl_down(v, 4);  v += __shfl_down(v, 2);  v += __shfl_down(v, 1);
    return v;
}
// block float-sum; result valid on thread 0
__device__ float bred(float v) {
    __shared__ float sb[16];
    const int lane = threadIdx.x & 63, w = threadIdx.x >> 6;
    const int nw = blockDim.x >> 6;
    v = wred(v);
    if (lane == 0) sb[w] = v;
    __syncthreads();
    float r = 0.0f;
    if (threadIdx.x == 0) for (int i = 0; i < nw; ++i) r += sb[i];
    __syncthreads();
    return r;
}

// hard flag: cand shortfall OR any wave-region overflow. 1024 threads.
__device__ bool derive_hard(const unsigned* __restrict__ ws, unsigned Kneg) {
    __shared__ unsigned rt[16], ro[16];
    __shared__ unsigned flag;
    const int t = threadIdx.x, lane = t & 63, w = t >> 6;
    unsigned tot = 0u, ov = 0u;
    for (unsigned i = t; i < NWAVES; i += 1024) {
        unsigned cc = ws[OFF_CNT + i];
        tot += cc & 0x7FFFFFFFu;
        ov |= cc >> 31;
    }
    for (int o = 32; o; o >>= 1) {
        tot += (unsigned)__shfl_down((int)tot, o);
        ov |= (unsigned)__shfl_down((int)ov, o);
    }
    if (lane == 0) { rt[w] = tot; ro[w] = ov; }
    __syncthreads();
    if (t == 0) {
        unsigned T = 0, O = 0;
        for (int i = 0; i < 16; ++i) { T += rt[i]; O |= ro[i]; }
        flag = (T < Kneg) || O;
    }
    __syncthreads();
    return flag != 0u;
}

// load per-wave counts (min(count,REG)) into LDS table. 1024 threads.
__device__ void load_cnt16(const unsigned* __restrict__ ws, unsigned short* cnt16) {
    for (unsigned i = threadIdx.x; i < NWAVES; i += 1024) {
        unsigned c = ws[OFF_CNT + i] & 0x7FFFFFFFu;
        cnt16[i] = (unsigned short)(c < REG ? c : REG);
    }
    __syncthreads();
}

// descending rank-select over NP x NB global partial counts. Coalesced:
// thread t owns bin NB-1-t, loops partials. 1024 threads. R >= 1.
__device__ void scanP(const unsigned* __restrict__ hp, unsigned R,
                      unsigned* b_out, unsigned* r_out) {
    __shared__ unsigned sums[1024];
    __shared__ unsigned res[2];
    const int t = threadIdx.x;
    const int bin = (NB - 1) - t;
    unsigned s = 0;
    for (int p = 0; p < NP; ++p) s += hp[p * NB + bin];
    if (t == 0) { res[0] = 0u; res[1] = 1u; }
    sums[t] = s;
    __syncthreads();
    for (int off = 1; off < 1024; off <<= 1) {
        unsigned v = (t >= off) ? sums[t - off] : 0u;
        __syncthreads();
        sums[t] += v;
        __syncthreads();
    }
    const unsigned incl = sums[t], excl = incl - s;
    if (excl < R && incl >= R) { res[0] = (unsigned)bin; res[1] = R - excl; }
    __syncthreads();
    *b_out = res[0];
    *r_out = res[1];
    __syncthreads();
}

// descending rank-select over an LDS hist + fsum-above. 1024 threads.
__device__ void scanL(const unsigned* __restrict__ cnt, const float* __restrict__ fsm,
                      int nbins, unsigned R,
                      unsigned* b_out, unsigned* r_out, float* fa_out) {
    __shared__ unsigned sums[1024];
    __shared__ unsigned res[2];
    __shared__ float sred;
    const int t = threadIdx.x;
    const int per = nbins >> 10;           // 1 or 2
    unsigned local[2];
    unsigned s = 0;
    for (int j = 0; j < per; ++j) {
        local[j] = cnt[nbins - 1 - (t * per + j)];
        s += local[j];
    }
    if (t == 0) { res[0] = 0u; res[1] = 1u; sred = 0.0f; }
    sums[t] = s;
    __syncthreads();
    for (int off = 1; off < 1024; off <<= 1) {
        unsigned v = (t >= off) ? sums[t - off] : 0u;
        __syncthreads();
        sums[t] += v;
        __syncthreads();
    }
    const unsigned incl = sums[t], excl = incl - s;
    if (excl < R && incl >= R) {
        unsigned cum = excl;
        for (int j = 0; j < per; ++j) {
            if (cum + local[j] >= R) {
                res[0] = (unsigned)(nbins - 1 - (t * per + j));
                res[1] = R - cum;
                break;
            }
            cum += local[j];
        }
    }
    __syncthreads();
    const unsigned b = res[0];
    float f = 0.0f;
    for (int j = (int)b + 1 + t; j < nbins; j += 1024) f += fsm[j];
    f = wred(f);
    if ((t & 63) == 0) atomicAdd(&sred, f);
    __syncthreads();
    *b_out = b;
    *r_out = res[1];
    if (t == 0) *fa_out = sred;
    __syncthreads();
}

// exact top-R softplus sum by 3-level (11/11/10-bit) radix select on FULL
// 32-bit keys. One block, 1024 threads. Source: LDS key buffer (stream=false)
// or negatives streamed from x,y (stream=true). Result valid on thread 0.
__device__ float select_any(const unsigned* __restrict__ lkeys, unsigned m3,
                            const float* __restrict__ x, const float* __restrict__ y,
                            int n, bool stream, unsigned R) {
    __shared__ unsigned cnt[2048];
    __shared__ float fsm[2048];
    const int t = threadIdx.x;
    unsigned prefix = 0u, mask = 0u;
    float above = 0.0f;                    // thread 0 only
    const int sh[3] = {21, 10, 0};
    const int nb[3] = {2048, 2048, 1024};
    for (int l = 0; l < 3; ++l) {
        for (int i = t; i < nb[l]; i += 1024) { cnt[i] = 0u; fsm[i] = 0.0f; }
        __syncthreads();
        if (!stream) {
            for (unsigned i = t; i < m3; i += 1024) {
                unsigned k = lkeys[i];
                if ((k & mask) == prefix) {
                    unsigned b = (k >> sh[l]) & (unsigned)(nb[l] - 1);
                    atomicAdd(&cnt[b], 1u);
                    atomicAdd(&fsm[b], softplusf(key2f(k)));
                }
            }
        } else {
            for (unsigned i = t; i < (unsigned)n; i += 1024) {
                if (y[i] == 0.0f) {
                    unsigned k = f2key(x[i]);
                    if ((k & mask) == prefix) {
                        unsigned b = (k >> sh[l]) & (unsigned)(nb[l] - 1);
                        atomicAdd(&cnt[b], 1u);
                        atomicAdd(&fsm[b], softplusf(key2f(k)));
                    }
                }
            }
        }
        __syncthreads();
        unsigned b, r;
        float fa;
        scanL(cnt, fsm, nb[l], R, &b, &r, &fa);
        if (t == 0) above += fa;
        R = r;
        prefix |= b << sh[l];
        mask |= (unsigned)(nb[l] - 1) << sh[l];
        __syncthreads();
    }
    return above + (float)R * softplusf(key2f(prefix));
}

// ---- k_main: pos partial sums + per-wave-region compact. ZERO atomics. ----
__global__ __launch_bounds__(256)
void k_main(const float* __restrict__ x, const float* __restrict__ y,
            unsigned* __restrict__ ws, unsigned cap_words, int n) {
    const int tid = threadIdx.x;
    const int lane = tid & 63;
    const unsigned waveid = blockIdx.x * 4 + (tid >> 6);
    unsigned* cand = ws + OFF_CAND;
    const unsigned base = waveid * REG;

    if (blockIdx.x == 0)                   // zero control words + slots
        for (int i = tid; i < 128; i += 256) ws[i] = 0u;

    float ps = 0.0f;
    unsigned cur = 0u, ovf = 0u;
    const int n4 = n >> 2;
    const float4* x4 = (const float4*)x;
    const float4* y4 = (const float4*)y;
    const unsigned gtid = blockIdx.x * blockDim.x + tid;
    const unsigned gstride = gridDim.x * blockDim.x;
    for (unsigned i = gtid; i < (unsigned)n4; i += gstride) {
        float4 xv = x4[i];
        float4 yv = y4[i];
        float xs[4] = {xv.x, xv.y, xv.z, xv.w};
        float ys[4] = {yv.x, yv.y, yv.z, yv.w};
#pragma unroll
        for (int c = 0; c < 4; ++c) {
            bool pos = ys[c] > 0.0f;
            if (pos) ps += softplusf(-xs[c]);
            unsigned k = f2key(xs[c]);
            bool cnd = (!pos) && (k >= K0);
            unsigned long long mask = __ballot(cnd);
            if (mask) {
                if (cnd) {
                    unsigned slot = cur + (unsigned)__popcll(mask & ((1ull << lane) - 1ull));
                    unsigned gi = base + slot;
                    if (slot < REG && gi < cap_words) cand[gi] = k;
                    else ovf = 1u;
                }
                cur += (unsigned)__popcll(mask);
            }
        }
    }
    // tail (n % 4): wave 0 only; ballot keeps cur wave-uniform
    if (waveid == 0) {
        for (int i = (n & ~3) + lane; i < n; i += 64) {
            float xs = x[i];
            bool pos = y[i] > 0.0f;
            if (pos) ps += softplusf(-xs);
            unsigned k = f2key(xs);
            bool cnd = (!pos) && (k >= K0);
            unsigned long long mask = __ballot(cnd);
            if (mask) {
                if (cnd) {
                    unsigned slot = cur + (unsigned)__popcll(mask & ((1ull << lane) - 1ull));
                    unsigned gi = base + slot;
                    if (slot < REG && gi < cap_words) cand[gi] = k;
                    else ovf = 1u;
                }
                cur += (unsigned)__popcll(mask);
            }
        }
    }
    if (base + REG > cap_words) ovf = 1u;
    ps = wred(ps);
    unsigned anyovf = (__ballot(ovf != 0u) != 0ull) ? 0x80000000u : 0u;
    if (lane == 0) {
        ws[OFF_CNT + waveid] = (cur & 0x7FFFFFFFu) | anyovf;
        ((float*)ws)[OFF_POSP + waveid] = ps;
    }
}

// ---- k_h1 (256x1024): pure-store partial count+fsum hists over cand ----
__global__ __launch_bounds__(1024)
void k_h1(unsigned* __restrict__ ws, const int* __restrict__ pos_num) {
    __shared__ unsigned hc[NB];
    __shared__ float hf[NB];
    __shared__ unsigned short cnt16[NWAVES];
    const int t = threadIdx.x;
    const unsigned Kneg = (unsigned)(pos_num[0] * 3);
    if (derive_hard(ws, Kneg)) return;     // winner streams x,y in hard mode
    load_cnt16(ws, cnt16);
    if (t < NB) { hc[t] = 0u; hf[t] = 0.0f; }
    __syncthreads();
    const unsigned* cand = ws + OFF_CAND;
    const unsigned gstride = NP * 1024;
    for (unsigned i = blockIdx.x * 1024 + t; i < (unsigned)CANDW; i += gstride) {
        if ((i & (REG - 1)) < (unsigned)cnt16[i >> 8]) {
            unsigned k = cand[i];
            unsigned b = (k - K0) >> 14;   // exact for x in [1,4)
            b = b > (NB - 1) ? (NB - 1) : b;
            atomicAdd(&hc[b], 1u);
            atomicAdd(&hf[b], softplusf(key2f(k)));
        }
    }
    __syncthreads();
    if (t < NB) {
        ws[OFF_HC + blockIdx.x * NB + t] = hc[t];                 // pure store
        ((float*)ws)[OFF_HF + blockIdx.x * NB + t] = hf[t];
    }
}

// ---- k_h2 (64x1024): scan; boundary extract; slot fold; ticket finalize ----
__global__ __launch_bounds__(1024)
void k_h2(const float* __restrict__ x, const float* __restrict__ y,
          unsigned* __restrict__ ws, const int* __restrict__ pos_num,
          float* __restrict__ out, int n, unsigned side_cap) {
    __shared__ unsigned lbuf[LBUF];
    __shared__ unsigned short cnt16[NWAVES];
    __shared__ unsigned lcnt, gbase, sticket;
    const int t = threadIdx.x;
    const int p = pos_num[0];
    const unsigned Kneg = (unsigned)(p * 3);
    const bool hard = derive_hard(ws, Kneg);
    unsigned b1 = 0, r1 = Kneg;
    if (!hard) {
        scanP(ws + OFF_HC, Kneg, &b1, &r1);
        load_cnt16(ws, cnt16);
        if (t == 0) lcnt = 0u;
        __syncthreads();
        const unsigned* cand = ws + OFF_CAND;
        unsigned* side = ws + OFF_SIDE;
        const unsigned gstride = NH2 * 1024;
        for (unsigned i = blockIdx.x * 1024 + t; i < (unsigned)CANDW; i += gstride) {
            if ((i & (REG - 1)) < (unsigned)cnt16[i >> 8]) {
                unsigned k = cand[i];
                unsigned b = (k - K0) >> 14;
                b = b > (NB - 1) ? (NB - 1) : b;
                if (b == b1) {             // ~35 hits/block: LDS atomic fine
                    unsigned q = atomicAdd(&lcnt, 1u);
                    if (q < LBUF) lbuf[q] = k;
                }
            }
        }
        __syncthreads();
        const unsigned m = lcnt < LBUF ? lcnt : LBUF;
        if (t == 0) {
            gbase = atomicAdd(&ws[OFF_SIDE_CNT], m);   // ONE per block
            if (lcnt > LBUF) atomicOr(&ws[OFF_FLAGS], 1u);
        }
        __syncthreads();
        unsigned oob = 0u;
        for (unsigned i = t; i < m; i += 1024) {
            unsigned gi = gbase + i;
            if (gi < side_cap) side[gi] = lbuf[i];
            else oob = 1u;
        }
        if (oob) atomicOr(&ws[OFF_FLAGS], 1u);
        // slot: pos slice + fsum-above-b1 of this block's 4 partials
        float s = 0.0f;
        if (t < NWAVES / NH2)
            s += ((float*)ws)[OFF_POSP + blockIdx.x * (NWAVES / NH2) + t];
        if ((unsigned)t > b1) {
            const float* hf = (const float*)(ws + OFF_HF);
#pragma unroll
            for (int q = 0; q < NP / NH2; ++q)
                s += hf[(blockIdx.x * (NP / NH2) + q) * NB + t];
        }
        s = bred(s);
        if (t == 0) ((float*)ws)[OFF_SLOT + blockIdx.x] = s;
    }
    // ---- ticket: last block finalizes ----
    __threadfence();
    if (t == 0) sticket = atomicAdd(&ws[OFF_TICKET], 1u);
    __syncthreads();
    if (sticket != NH2 - 1) return;
    // winner: coherent reads of peer-written data (atomic RMW returns fresh)
    bool whard = hard;
    unsigned m3 = 0;
    if (!whard) {
        if (atomicOr(&ws[OFF_FLAGS], 0u)) whard = true;
        else {
            m3 = atomicAdd(&ws[OFF_SIDE_CNT], 0u);
            if (m3 > LBUF || m3 > side_cap) whard = true;
        }
    }
    float total;
    if (!whard) {
        float base = 0.0f;
        if (t < NH2) base = atomicAdd(&((float*)ws)[OFF_SLOT + t], 0.0f);
        base = bred(base);
        for (unsigned i = t; i < m3; i += 1024)
            lbuf[i] = atomicOr(&ws[OFF_SIDE + i], 0u);   // coherent copy to LDS
        __syncthreads();
        total = base + select_any(lbuf, m3, x, y, n, false, r1);
    } else {
        float psum = 0.0f;                 // POSP written in prev dispatch: plain ok
        for (unsigned i = t; i < NWAVES; i += 1024)
            psum += ((float*)ws)[OFF_POSP + i];
        psum = bred(psum);
        total = psum + select_any(nullptr, 0u, x, y, n, true, Kneg);
    }
    if (t == 0) out[0] = total / (float)(4 * p);
}

extern "C" void kernel_launch(void* const* d_in, const int* in_sizes, int n_in,
                              void* d_out, int out_size, void* d_ws, size_t ws_size,
                              hipStream_t stream) {
    const float* x = (const float*)d_in[0];
    const float* y = (const float*)d_in[1];
    const int* pos_num = (const int*)d_in[2];
    float* out = (float*)d_out;
    const int n = in_sizes[0];

    unsigned* ws = (unsigned*)d_ws;
    const size_t wsw = ws_size / 4;
    unsigned cap_words = 0u;
    if (wsw > (size_t)OFF_CAND) cap_words = (unsigned)(wsw - OFF_CAND);
    if (cap_words > (unsigned)CANDW) cap_words = (unsigned)CANDW;
    unsigned side_cap = 0u;
    if (wsw > (size_t)OFF_SIDE) side_cap = (unsigned)(wsw - OFF_SIDE);
    if (side_cap > SIDE_CAP_MAX) side_cap = SIDE_CAP_MAX;

    k_main<<<2048, 256, 0, stream>>>(x, y, ws, cap_words, n);
    k_h1<<<NP, 1024, 0, stream>>>(ws, pos_num);
    k_h2<<<NH2, 1024, 0, stream>>>(x, y, ws, pos_num, out, n, side_cap);
}